// Round 11
// baseline (23869.293 us; speedup 1.0000x reference)
//
#include <hip/hip_runtime.h>
#include <hip/hip_bf16.h>
#include <stdint.h>

typedef _Float16 f16;
typedef _Float16 f16x8 __attribute__((ext_vector_type(8)));
typedef float f32x4 __attribute__((ext_vector_type(4)));
typedef unsigned long long u64;

#define LDF16X8(p) (*reinterpret_cast<const f16x8*>(p))

// coherent (agent-scope) 16B h load as 2x8B relaxed atomics
__device__ __forceinline__ f16x8 ld_h(const f16* p) {
  union { u64 q[2]; f16x8 v; } u;
  u.q[0] = __hip_atomic_load((const u64*)p,     __ATOMIC_RELAXED, __HIP_MEMORY_SCOPE_AGENT);
  u.q[1] = __hip_atomic_load((const u64*)p + 1, __ATOMIC_RELAXED, __HIP_MEMORY_SCOPE_AGENT);
  return u.v;
}

// ---------------- f32 -> f16 convert ----------------
__global__ __launch_bounds__(256) void k_cvt(const float* __restrict__ in,
                                             f16* __restrict__ out, int n) {
  int i = (blockIdx.x * 256 + threadIdx.x) * 4;
  if (i + 3 < n) {
    float4 v = *reinterpret_cast<const float4*>(in + i);
    out[i + 0] = (f16)v.x; out[i + 1] = (f16)v.y;
    out[i + 2] = (f16)v.z; out[i + 3] = (f16)v.w;
  } else {
    for (; i < n; ++i) out[i] = (f16)in[i];
  }
}

// ---------------- GEMM (M,K)x(N,K)^T + BN -> wperm layout ----------------
// Computes wrow[m,e] = BN_e(sum_k A[m,k]*B[e,k]) and stores it permuted for the
// scan: wperm[((wg*512 + t)*32 + cb)*64 + c], where m = cb*512+t and
// e<1024: wg=e>>5, c=e&31 ; e>=1024: wg=(e-1024)>>5, c=32+(e&31).
__global__ __launch_bounds__(256) void k_gemm_bn(
    const f16* __restrict__ A,    // (M,K)
    const f16* __restrict__ B,    // (N,K)
    const float* __restrict__ gamma, const float* __restrict__ beta,
    const float* __restrict__ mean, const float* __restrict__ var,
    f16* __restrict__ wperm,      // [32][512][32][64]
    int M, int N, int K) {
  __shared__ f16 Al[4 * 128 * 8];
  __shared__ f16 Bl[4 * 128 * 8];
  const int tid = threadIdx.x;
  const int lane = tid & 63, wid = tid >> 6;
  const int wm = wid >> 1, wn = wid & 1;
  const int row0 = blockIdx.x * 128, col0 = blockIdx.y * 128;

  f32x4 acc[4][4] = {};

  const int sR = tid >> 1;         // 0..127 staging row
  const int sk8 = (tid & 1) * 2;   // k8 block 0 or 2

  for (int k0 = 0; k0 < K; k0 += 32) {
    __syncthreads();
    {
      const f16* srcA = A + (size_t)(row0 + sR) * K + k0 + sk8 * 8;
      uint4 a0 = *reinterpret_cast<const uint4*>(srcA);
      uint4 a1 = *reinterpret_cast<const uint4*>(srcA + 8);
      *reinterpret_cast<uint4*>(&Al[(sk8 * 128 + sR) * 8]) = a0;
      *reinterpret_cast<uint4*>(&Al[((sk8 + 1) * 128 + sR) * 8]) = a1;
      const f16* srcB = B + (size_t)(col0 + sR) * K + k0 + sk8 * 8;
      uint4 b0 = *reinterpret_cast<const uint4*>(srcB);
      uint4 b1 = *reinterpret_cast<const uint4*>(srcB + 8);
      *reinterpret_cast<uint4*>(&Bl[(sk8 * 128 + sR) * 8]) = b0;
      *reinterpret_cast<uint4*>(&Bl[((sk8 + 1) * 128 + sR) * 8]) = b1;
    }
    __syncthreads();

    const int k8 = lane >> 4, r16 = lane & 15;
    f16x8 af[4], bfr[4];
#pragma unroll
    for (int m = 0; m < 4; ++m)
      af[m] = LDF16X8(&Al[(k8 * 128 + wm * 64 + m * 16 + r16) * 8]);
#pragma unroll
    for (int n = 0; n < 4; ++n)
      bfr[n] = LDF16X8(&Bl[(k8 * 128 + wn * 64 + n * 16 + r16) * 8]);
#pragma unroll
    for (int m = 0; m < 4; ++m)
#pragma unroll
      for (int n = 0; n < 4; ++n)
        acc[m][n] = __builtin_amdgcn_mfma_f32_16x16x32_f16(af[m], bfr[n], acc[m][n], 0, 0, 0);
  }

  // epilogue: BN per output column e, store f16 into wperm layout
#pragma unroll
  for (int n = 0; n < 4; ++n) {
    int e = col0 + wn * 64 + n * 16 + (lane & 15);
    float g = gamma[e], be = beta[e], mu = mean[e], va = var[e];
    float s = g * rsqrtf(va + 1e-5f);
    float sh = be - mu * s;
    int wg_e = (e < 1024) ? (e >> 5) : ((e - 1024) >> 5);
    int c    = (e & 31) + ((e < 1024) ? 0 : 32);
#pragma unroll
    for (int m = 0; m < 4; ++m) {
#pragma unroll
      for (int r = 0; r < 4; ++r) {
        int row = row0 + wm * 64 + m * 16 + (lane >> 4) * 4 + r;
        int cb = row >> 9, tt = row & 511;
        wperm[(((size_t)wg_e * 512 + tt) * 32 + cb) * 64 + c] =
            (f16)(acc[m][n][r] * s + sh);
      }
    }
  }
}

// ---------------- persistent LiGRU scan (one launch per layer) ----------------
// 32 wgs x 1024 thr (16 waves). wg owns j-cols [j0, j0+32): 64 gate outputs.
// U slice (64 rows x 1024) f16 in dynamic LDS (128KB) + gl[2][32][64] f32 (16KB).
// Wave roles: mt=wid&1 (batch half), nt=(wid>>1)&3 (output quarter), kq=wid>>3 (k half).
// h/flags via relaxed agent-scope atomics (coherence point), no cache-wide fences.
__global__ __launch_bounds__(1024, 1) void k_scan(
    const float* __restrict__ U,    // (2048,1024) f32
    const f16* __restrict__ wperm,  // [32][512][32][64] f16 (wg-private)
    f16* __restrict__ hpub,         // [2][32][1024] f16
    f16* __restrict__ xoutH,        // (16384,1024) f16 (if !last)
    float* __restrict__ xoutF,      // (16384,1024) f32 (if last)
    float* __restrict__ hh,         // (32,3,1024) f32
    unsigned* __restrict__ flags,   // [32][32] uints (128B stride per wg)
    int layer, int last) {
  extern __shared__ char smem[];
  f16* Ul  = (f16*)smem;                       // 64*1024 f16, k-block-major
  float* gl = (float*)(smem + 131072);         // [2][32][64] f32

  const int tid = threadIdx.x;
  const int lane = tid & 63, wid = tid >> 6;
  const int mt = wid & 1, nt = (wid >> 1) & 3, kq = wid >> 3;
  const int j0 = blockIdx.x * 32;
  const int r16 = lane & 15, kg4 = lane >> 4;

  // stage U slice -> LDS (f32 -> f16): rows = 32 a-rows then 32 z-rows
  for (int i = tid; i < 64 * 1024; i += 1024) {
    int e = i >> 10, k = i & 1023;
    int erow = (e < 32) ? (j0 + e) : (1024 + j0 + e - 32);
    Ul[((k >> 3) * 64 + e) * 8 + (k & 7)] = (f16)U[(size_t)erow * 1024 + k];
  }
  __syncthreads();

  const int cb = tid >> 5;  // combine: batch 0..31
  const int cj = tid & 31;  // combine: j-col 0..31
  float hreg = 0.f;         // exact f32 h for (cb, j0+cj)

  // prefetch w for t=0 (wg-private contiguous block)
  float wa, wz;
  {
    size_t base = ((size_t)(blockIdx.x * 512 + 0) * 32 + cb) * 64;
    wa = (float)wperm[base + cj];
    wz = (float)wperm[base + 32 + cj];
  }

  for (int t = 0; t < 512; ++t) {
    const int cur = t & 1, nxt = cur ^ 1;

    // ---- matvec: gates[32 x 64] partial over this wave's k-half ----
    f32x4 acc = {};
    const f16* hbase = hpub + cur * 32768 + (size_t)(mt * 16 + r16) * 1024 + kq * 512 + kg4 * 8;
#pragma unroll
    for (int kk = 0; kk < 16; ++kk) {
      f16x8 a = ld_h(hbase + kk * 32);                       // coherent read
      f16x8 b = LDF16X8(&Ul[((kq * 64 + kk * 4 + kg4) * 64 + nt * 16 + r16) * 8]);
      acc = __builtin_amdgcn_mfma_f32_16x16x32_f16(a, b, acc, 0, 0, 0);
    }
#pragma unroll
    for (int r = 0; r < 4; ++r)
      gl[(kq * 32 + mt * 16 + kg4 * 4 + r) * 64 + nt * 16 + r16] = acc[r];
    __syncthreads();

    // ---- combine: one (batch, j) per thread ----
    {
      float apre = gl[cb * 64 + cj]        + gl[(32 + cb) * 64 + cj]        + wa;
      float zpre = gl[cb * 64 + 32 + cj]   + gl[(32 + cb) * 64 + 32 + cj]   + wz;
      float z = 1.f / (1.f + expf(-zpre));
      float hn = z * hreg + (1.f - z) * fmaxf(apre, 0.f);
      hreg = hn;
      // pack 2 f16 per dword, agent-scope store (even cj lanes)
      f16 hf = (f16)hn;
      unsigned hb = (unsigned)__builtin_bit_cast(unsigned short, hf);
      unsigned nb = __shfl_down(hb, 1, 64);
      if ((cj & 1) == 0)
        __hip_atomic_store((unsigned*)(hpub + nxt * 32768 + cb * 1024 + j0 + cj),
                           hb | (nb << 16), __ATOMIC_RELAXED, __HIP_MEMORY_SCOPE_AGENT);
      size_t xoff = (size_t)(cb * 512 + t) * 1024 + j0 + cj;
      if (last) xoutF[xoff] = hn;
      else      xoutH[xoff] = (f16)hn;
    }

    // ---- barrier: arrive (after h stores acked), overlap w prefetch, wait ----
    __syncthreads();   // vmcnt(0) per wave: h stores acked at coherence point
    if (tid == 0)
      __hip_atomic_store(&flags[(size_t)blockIdx.x * 32], t + 1u,
                         __ATOMIC_RELAXED, __HIP_MEMORY_SCOPE_AGENT);
    if (t + 1 < 512) {   // prefetch next w while waiting
      size_t base = ((size_t)(blockIdx.x * 512 + t + 1) * 32 + cb) * 64;
      wa = (float)wperm[base + cj];
      wz = (float)wperm[base + 32 + cj];
    }
    if (tid < 32) {      // 32 lanes poll 32 flags
      const unsigned tgt = t + 1u;
      while (__hip_atomic_load(&flags[(size_t)tid * 32], __ATOMIC_RELAXED,
                               __HIP_MEMORY_SCOPE_AGENT) < tgt)
        __builtin_amdgcn_s_sleep(1);
    }
    __syncthreads();
  }

  // final hidden state
  hh[(size_t)(cb * 3 + layer) * 1024 + j0 + cj] = hreg;
}

// ---------------- launcher ----------------
extern "C" void kernel_launch(void* const* d_in, const int* in_sizes, int n_in,
                              void* d_out, int out_size, void* d_ws, size_t ws_size,
                              hipStream_t stream) {
  const float* x     = (const float*)d_in[0];
  const float* W     = (const float*)d_in[1];
  const float* U     = (const float*)d_in[2];
  const float* gamma = (const float*)d_in[3];
  const float* beta  = (const float*)d_in[4];
  const float* rmean = (const float*)d_in[5];
  const float* rvar  = (const float*)d_in[6];
  float* outX  = (float*)d_out;                       // (32,512,1024) f32
  float* outHH = outX + (size_t)32 * 512 * 1024;      // (32,3,1024)  f32

  // Inter-layer f16 activations live in the d_out outX region (33.5 MB of 67 MB):
  // dead by the time the last layer's scan overwrites it with f32 output.
  f16* xb = (f16*)d_out;

  char* ws = (char*)d_ws;
  f16* wperm = (f16*)(ws);                // 32*512*32*64*2 = 67,108,864 B
  f16* Wb    = (f16*)(ws + 67108864);     //  2048*1024*2  =  4,194,304 B
  f16* hpub  = (f16*)(ws + 71303168);     //  2*32*1024*2  =    131,072 B
  unsigned* flags = (unsigned*)(ws + 71434240);  // 32*32*4 = 4,096 B
  // total d_ws usage: ~71.5 MB

  // x -> f16
  k_cvt<<<16384, 256, 0, stream>>>(x, xb, 16777216);

  for (int l = 0; l < 3; ++l) {
    // W[l] -> f16
    k_cvt<<<2048, 256, 0, stream>>>(W + (size_t)l * 2097152, Wb, 2097152);
    // w = BN(x_l @ W^T), stored directly in scan-private layout
    k_gemm_bn<<<dim3(128, 16), 256, 0, stream>>>(
        xb, Wb, gamma + l * 2048, beta + l * 2048, rmean + l * 2048, rvar + l * 2048,
        wperm, 16384, 2048, 1024);
    // reset h and flags, then scan
    hipMemsetAsync(hpub, 0, 131072, stream);
    hipMemsetAsync(flags, 0, 4096, stream);
    k_scan<<<32, 1024, 147456, stream>>>(
        U + (size_t)l * 2097152, wperm, hpub,
        xb, outX, outHH, flags, l, (l == 2) ? 1 : 0);
  }
}